// Round 14
// baseline (1199.532 us; speedup 1.0000x reference)
//
#include <hip/hip_runtime.h>
#include <hip/hip_bf16.h>
#include <hip/hip_fp16.h>
#include <math.h>

// Problem constants: N=100000 nodes, E=1600000 edges, D=128, H=256, B=64.
// R5: 4208us. R6: 1981us (ln_stats LDS fix). R7: 1719us (gemm reg-tile).
// R10: 1420us (fp16 gather). R12: 1134us (MFMA f16 gemm). R13: 1079us
// (agg 16B/lane; agg now pinned at ~3.2TB/s random-fetch ceiling).
// R14: fuse LN stats into GEMM epilogue (stats from fp32 regs) + store h fp16
// -> removes 3 ln_stats dispatches and ~450MB of h traffic.
#define HDIM 256
#define NGRAPH 64
#define SCAN_CHUNK 2048  // 256 threads x 8 elems

__device__ inline __half2 u2h2(unsigned u) { return *reinterpret_cast<__half2*>(&u); }
__device__ inline unsigned h22u(__half2 h) { return *reinterpret_cast<unsigned*>(&h); }

typedef _Float16 f16x8 __attribute__((ext_vector_type(8)));
typedef float    f32x4 __attribute__((ext_vector_type(4)));

// ---------------------------------------------------------------------------
// in-degree count (int atomics)
__global__ void deg_count_k(const int* __restrict__ dst, int* __restrict__ deg, int E, int n) {
    int i = blockIdx.x * blockDim.x + threadIdx.x;
    if (i < E) {
        int d = dst[i];
        if ((unsigned)d < (unsigned)n) atomicAdd(&deg[d], 1);
    }
}

// dinv[i] = 1/sqrt(in_deg[i] + 1)
__global__ void dinv_k(const int* __restrict__ deg, float* __restrict__ dinv, int n) {
    int i = blockIdx.x * blockDim.x + threadIdx.x;
    if (i < n) dinv[i] = 1.0f / sqrtf((float)deg[i] + 1.0f);
}

// last node index of each (sorted, consecutive) graph id
__global__ void last_idx_k(const int* __restrict__ batch, int* __restrict__ lastidx, int n) {
    int i = blockIdx.x * blockDim.x + threadIdx.x;
    if (i < n) {
        int b = batch[i];
        if ((i == n - 1 || batch[i + 1] != b) && b >= 0 && b < NGRAPH) lastidx[b] = i;
    }
}

// convert fp32 -> fp16 table (4 elems/thread)
__global__ void cvt_x_k(const float* __restrict__ x, __half* __restrict__ xh, long n4) {
    long i = (long)blockIdx.x * blockDim.x + threadIdx.x;
    if (i < n4) {
        float4 v = *(const float4*)(x + i * 4);
        __half2 p0 = __float22half2_rn(make_float2(v.x, v.y));
        __half2 p1 = __float22half2_rn(make_float2(v.z, v.w));
        uint2 st; st.x = h22u(p0); st.y = h22u(p1);
        *(uint2*)(xh + i * 4) = st;
    }
}

// W [K][256] fp32 -> Wt [256][K] fp16 (coalesced read, scattered 2B write; tiny)
__global__ void cvt_w_k(const float* __restrict__ W, __half* __restrict__ Wt, int K) {
    int idx = blockIdx.x * 256 + threadIdx.x;
    int k = idx >> 8, c = idx & 255;
    if (k < K) Wt[(size_t)c * K + k] = __float2half(W[(size_t)k * HDIM + c]);
}

// --------------------------- exclusive prefix scan -------------------------
__global__ __launch_bounds__(256) void scan1_k(const int* __restrict__ deg,
                                               int* __restrict__ partial, int n) {
    __shared__ int sm[256];
    int t = threadIdx.x;
    int base = blockIdx.x * SCAN_CHUNK + t * 8;
    int s = 0;
#pragma unroll
    for (int j = 0; j < 8; j++) { int idx = base + j; if (idx < n) s += deg[idx]; }
    sm[t] = s; __syncthreads();
    for (int o = 128; o; o >>= 1) { if (t < o) sm[t] += sm[t + o]; __syncthreads(); }
    if (t == 0) partial[blockIdx.x] = sm[0];
}

__global__ __launch_bounds__(1024) void scan2_k(int* __restrict__ partial, int nb,
                                                int* __restrict__ rs, int n) {
    __shared__ int sm[1024];
    int t = threadIdx.x;
    int v = (t < nb) ? partial[t] : 0;
    sm[t] = v; __syncthreads();
    for (int o = 1; o < 1024; o <<= 1) {
        int add = (t >= o) ? sm[t - o] : 0;
        __syncthreads();
        sm[t] += add;
        __syncthreads();
    }
    if (t < nb) partial[t] = sm[t] - v;  // exclusive block offset
    if (t == nb - 1) rs[n] = sm[t];      // total edge count
}

__global__ __launch_bounds__(256) void scan3_k(const int* __restrict__ deg,
                                               const int* __restrict__ partial,
                                               int* __restrict__ rs, int* __restrict__ cur, int n) {
    __shared__ int sm[256];
    int t = threadIdx.x;
    int base = blockIdx.x * SCAN_CHUNK + t * 8;
    int loc[8]; int s = 0;
#pragma unroll
    for (int j = 0; j < 8; j++) {
        int idx = base + j;
        loc[j] = (idx < n) ? deg[idx] : 0;
        s += loc[j];
    }
    sm[t] = s; __syncthreads();
    int v = s;
    for (int o = 1; o < 256; o <<= 1) {
        int add = (t >= o) ? sm[t - o] : 0;
        __syncthreads();
        sm[t] += add;
        __syncthreads();
    }
    int run = partial[blockIdx.x] + sm[t] - v;  // exclusive prefix for this thread
#pragma unroll
    for (int j = 0; j < 8; j++) {
        int idx = base + j;
        if (idx < n) { rs[idx] = run; cur[idx] = run; }
        run += loc[j];
    }
}

// scatter edges into CSR buckets (int atomics on cursors, ~E ops total)
__global__ void scatter_k(const int* __restrict__ src, const int* __restrict__ dst,
                          int* __restrict__ cur, int* __restrict__ csr, int E, int n) {
    int e = blockIdx.x * blockDim.x + threadIdx.x;
    if (e < E) {
        int d = dst[e], s = src[e];
        if ((unsigned)d < (unsigned)n && (unsigned)s < (unsigned)n) {
            int pos = atomicAdd(&cur[d], 1);
            csr[pos] = s;
        }
    }
}

// ---------------------------------------------------------------------------
// CSR aggregation, atomic-free. 16B/lane vector loads; NSUB edges processed
// concurrently by sub-waves; shfl_xor merge. (R13)
// z[i] = dinv[i] * sum_{s in in(i)} dinv[s]*x[s]  +  dinv[i]^2 * x[i]
template <int DIM>
__global__ __launch_bounds__(256) void agg_csr_k(
    const int* __restrict__ rs, const int* __restrict__ csr,
    const __half* __restrict__ xin, const float* __restrict__ dinv,
    __half* __restrict__ z, int n) {
    constexpr int LPR  = DIM / 8;   // lanes per row (16B = 8 fp16 each): 32 or 16
    constexpr int NSUB = 64 / LPR;  // concurrent edges per wave: 2 or 4
    int wid  = (blockIdx.x * blockDim.x + threadIdx.x) >> 6;
    int lane = threadIdx.x & 63;
    int nw   = (gridDim.x * blockDim.x) >> 6;
    const int h  = lane / LPR;  // sub-wave id
    const int sl = lane % LPR;  // lane within row

    for (int i = wid; i < n; i += nw) {
        int j0 = rs[i], j1 = rs[i + 1];
        float acc[8];
#pragma unroll
        for (int v = 0; v < 8; v++) acc[v] = 0.0f;

        for (int jb = j0; jb < j1; jb += 64) {
            int m = j1 - jb; if (m > 64) m = 64;
            int   sj = (lane < m) ? csr[jb + lane] : 0;    // lane>=m: row 0, w=0
            float wj = (lane < m) ? dinv[sj] : 0.0f;
#pragma unroll 4
            for (int r = 0; r < m; r += NSUB) {
                int   s = __shfl(sj, r + h);   // r+h <= 63 always
                float w = __shfl(wj, r + h);
                const __half* xr = xin + (size_t)s * DIM + sl * 8;
                uint4 u = *(const uint4*)xr;   // 16B = 8 fp16
                float2 a0 = __half22float2(u2h2(u.x));
                float2 a1 = __half22float2(u2h2(u.y));
                float2 a2 = __half22float2(u2h2(u.z));
                float2 a3 = __half22float2(u2h2(u.w));
                acc[0] += a0.x * w; acc[1] += a0.y * w;
                acc[2] += a1.x * w; acc[3] += a1.y * w;
                acc[4] += a2.x * w; acc[5] += a2.y * w;
                acc[6] += a3.x * w; acc[7] += a3.y * w;
            }
        }

        // merge sub-wave partial sums (same columns, different edge subsets)
        if (NSUB == 4) {
#pragma unroll
            for (int v = 0; v < 8; v++) acc[v] += __shfl_xor(acc[v], 16);
        }
#pragma unroll
        for (int v = 0; v < 8; v++) acc[v] += __shfl_xor(acc[v], 32);

        if (h == 0) {
            float di  = dinv[i];
            float di2 = di * di;
            const __half* xr = xin + (size_t)i * DIM + sl * 8;
            uint4 u = *(const uint4*)xr;
            float2 a0 = __half22float2(u2h2(u.x));
            float2 a1 = __half22float2(u2h2(u.y));
            float2 a2 = __half22float2(u2h2(u.z));
            float2 a3 = __half22float2(u2h2(u.w));
            float o0 = di * acc[0] + di2 * a0.x, o1 = di * acc[1] + di2 * a0.y;
            float o2 = di * acc[2] + di2 * a1.x, o3 = di * acc[3] + di2 * a1.y;
            float o4 = di * acc[4] + di2 * a2.x, o5 = di * acc[5] + di2 * a2.y;
            float o6 = di * acc[6] + di2 * a3.x, o7 = di * acc[7] + di2 * a3.y;
            uint4 st;
            st.x = h22u(__float22half2_rn(make_float2(o0, o1)));
            st.y = h22u(__float22half2_rn(make_float2(o2, o3)));
            st.z = h22u(__float22half2_rn(make_float2(o4, o5)));
            st.w = h22u(__float22half2_rn(make_float2(o6, o7)));
            *(uint4*)(z + (size_t)i * DIM + sl * 8) = st;
        }
    }
}

// ---------------------------------------------------------------------------
// MFMA GEMM with fused LN-stats epilogue: h = z @ W + bias (fp16 out),
// per-graph sum/sumsq accumulated from fp32 registers via LDS rows ->
// LDS graph bins -> ~2 global atomics/block. (R14)
template <int K>
__global__ __launch_bounds__(256) void gcn_gemm_k(
    const __half* __restrict__ z, const __half* __restrict__ Wt,
    const float* __restrict__ bias, __half* __restrict__ hout,
    const int* __restrict__ batch, float* __restrict__ gsum,
    float* __restrict__ gsq, int n) {
    __shared__ float rowsum[32], rowsq[32];
    __shared__ float lgs[NGRAPH], lgq[NGRAPH];
    const int t   = threadIdx.x;
    const int wv  = t >> 6;
    const int l   = t & 63;
    const int l15 = l & 15;
    const int lhi = l >> 4;  // 0..3
    const int r0  = blockIdx.x * 32;
    const int c0  = wv * 64;

    if (t < 32) { rowsum[t] = 0.0f; rowsq[t] = 0.0f; }
    if (t < NGRAPH) { lgs[t] = 0.0f; lgq[t] = 0.0f; }

    f32x4 acc[2][4];
#pragma unroll
    for (int cg = 0; cg < 4; cg++) {
        float bv = bias[c0 + cg * 16 + l15];
        f32x4 b4 = {bv, bv, bv, bv};
        acc[0][cg] = b4;
        acc[1][cg] = b4;
    }

    int ra = r0 + l15;      if (ra >= n) ra = n - 1;  // clamped (stores guarded)
    int rb = r0 + 16 + l15; if (rb >= n) rb = n - 1;
    const __half* za = z + (size_t)ra * K + lhi * 8;
    const __half* zb = z + (size_t)rb * K + lhi * 8;
    const __half* wp0 = Wt + (size_t)(c0 + 0 * 16 + l15) * K + lhi * 8;
    const __half* wp1 = Wt + (size_t)(c0 + 1 * 16 + l15) * K + lhi * 8;
    const __half* wp2 = Wt + (size_t)(c0 + 2 * 16 + l15) * K + lhi * 8;
    const __half* wp3 = Wt + (size_t)(c0 + 3 * 16 + l15) * K + lhi * 8;

#pragma unroll
    for (int ks = 0; ks < K; ks += 32) {
        f16x8 a0 = *(const f16x8*)(za + ks);
        f16x8 a1 = *(const f16x8*)(zb + ks);
        f16x8 b0 = *(const f16x8*)(wp0 + ks);
        f16x8 b1 = *(const f16x8*)(wp1 + ks);
        f16x8 b2 = *(const f16x8*)(wp2 + ks);
        f16x8 b3 = *(const f16x8*)(wp3 + ks);
        acc[0][0] = __builtin_amdgcn_mfma_f32_16x16x32_f16(a0, b0, acc[0][0], 0, 0, 0);
        acc[1][0] = __builtin_amdgcn_mfma_f32_16x16x32_f16(a1, b0, acc[1][0], 0, 0, 0);
        acc[0][1] = __builtin_amdgcn_mfma_f32_16x16x32_f16(a0, b1, acc[0][1], 0, 0, 0);
        acc[1][1] = __builtin_amdgcn_mfma_f32_16x16x32_f16(a1, b1, acc[1][1], 0, 0, 0);
        acc[0][2] = __builtin_amdgcn_mfma_f32_16x16x32_f16(a0, b2, acc[0][2], 0, 0, 0);
        acc[1][2] = __builtin_amdgcn_mfma_f32_16x16x32_f16(a1, b2, acc[1][2], 0, 0, 0);
        acc[0][3] = __builtin_amdgcn_mfma_f32_16x16x32_f16(a0, b3, acc[0][3], 0, 0, 0);
        acc[1][3] = __builtin_amdgcn_mfma_f32_16x16x32_f16(a1, b3, acc[1][3], 0, 0, 0);
    }

    __syncthreads();  // LDS init visible

    // h store (fp16) + per-row partial stats into LDS
#pragma unroll
    for (int rg = 0; rg < 2; rg++) {
#pragma unroll
        for (int i = 0; i < 4; i++) {
            int ri = rg * 16 + lhi * 4 + i;
            int r  = r0 + ri;
            if (r < n) {
                __half* hp = hout + (size_t)r * HDIM + c0 + l15;
                float v0 = acc[rg][0][i], v1 = acc[rg][1][i];
                float v2 = acc[rg][2][i], v3 = acc[rg][3][i];
                hp[0]  = __float2half(v0);
                hp[16] = __float2half(v1);
                hp[32] = __float2half(v2);
                hp[48] = __float2half(v3);
                atomicAdd(&rowsum[ri], v0 + v1 + v2 + v3);
                atomicAdd(&rowsq[ri], v0 * v0 + v1 * v1 + v2 * v2 + v3 * v3);
            }
        }
    }
    __syncthreads();

    // rows -> graph bins (block rows span ~1-3 graphs; batch sorted)
    if (t < 32) {
        int r = r0 + t;
        if (r < n) {
            int bg = batch[r];
            if (bg < 0) bg = 0; if (bg >= NGRAPH) bg = NGRAPH - 1;
            atomicAdd(&lgs[bg], rowsum[t]);
            atomicAdd(&lgq[bg], rowsq[t]);
        }
    }
    __syncthreads();
    if (t < NGRAPH) {
        float s = lgs[t], q = lgq[t];
        if (s != 0.0f || q != 0.0f) {
            unsafeAtomicAdd(&gsum[t], s);
            unsafeAtomicAdd(&gsq[t], q);
        }
    }
}

// mean / rstd per graph (counts derived from last_idx of sorted batch)
__global__ void ln_fin_k(const float* __restrict__ gsum, const float* __restrict__ gsq,
                         const int* __restrict__ lastidx, float* __restrict__ mean,
                         float* __restrict__ rstd, int n) {
    int g = threadIdx.x;
    if (g >= NGRAPH) return;
    int last = lastidx[g];
    if (last < 0) last = 0; if (last >= n) last = n - 1;
    int prev = g ? lastidx[g - 1] : -1;
    if (prev < -1) prev = -1; if (prev >= n) prev = n - 1;
    float cnt = (float)(last - prev);
    if (cnt < 1.0f) cnt = 1.0f;
    float denom = cnt * (float)HDIM;
    float m = gsum[g] / denom;
    float v = gsq[g] / denom - m * m;
    if (v < 0.0f) v = 0.0f;
    mean[g] = m;
    rstd[g] = 1.0f / sqrtf(v + 1e-5f);
}

// h16out = tanh((h16 - mean)*rstd*w + b)  (fp16 in, fp32 math, fp16 out)
__global__ void ln_tanh_k(const __half* __restrict__ h, const int* __restrict__ batch,
                          const float* __restrict__ mean, const float* __restrict__ rstd,
                          const float* __restrict__ w, const float* __restrict__ b,
                          __half* __restrict__ h16, int n) {
    long gid = (long)blockIdx.x * blockDim.x + threadIdx.x;
    long total = (long)n * 64;
    if (gid >= total) return;
    int i  = (int)(gid >> 6);
    int c  = (int)(gid & 63) * 4;
    int bg = batch[i];
    if (bg < 0) bg = 0; if (bg >= NGRAPH) bg = NGRAPH - 1;
    float m = mean[bg], r = rstd[bg];
    uint2 u = *(const uint2*)(h + (size_t)i * HDIM + c);
    float2 a0 = __half22float2(u2h2(u.x));
    float2 a1 = __half22float2(u2h2(u.y));
    float4 w4 = *(const float4*)(w + c);
    float4 b4 = *(const float4*)(b + c);
    float v0 = tanhf((a0.x - m) * r * w4.x + b4.x);
    float v1 = tanhf((a0.y - m) * r * w4.y + b4.y);
    float v2 = tanhf((a1.x - m) * r * w4.z + b4.z);
    float v3 = tanhf((a1.y - m) * r * w4.w + b4.w);
    uint2 st;
    st.x = h22u(__float22half2_rn(make_float2(v0, v1)));
    st.y = h22u(__float22half2_rn(make_float2(v2, v3)));
    *(uint2*)(h16 + (size_t)i * HDIM + c) = st;
}

// gather the 64 last-node rows (fp16) of a layer output into xjk (fp32)
__global__ void extract_rows_k(const __half* __restrict__ x, const int* __restrict__ lastidx,
                               float* __restrict__ out, int n) {
    int g = blockIdx.x, c = threadIdx.x;
    int r = lastidx[g];
    if (r < 0) r = 0; if (r >= n) r = n - 1;
    out[(size_t)g * HDIM + c] = __half2float(x[(size_t)r * HDIM + c]);
}

// ---------------------------------------------------------------------------
// head: JK-cat [768] @ jk_w + jk_b -> tanh(fc1) -> fc2, one block per graph
__global__ __launch_bounds__(256) void final_mlp_k(
    const float* __restrict__ xjk,  // [3][64][256]
    const float* __restrict__ jk_w, const float* __restrict__ jk_b,
    const float* __restrict__ fc1_w, const float* __restrict__ fc1_b,
    const float* __restrict__ fc2_w, const float* __restrict__ fc2_b,
    float* __restrict__ out) {
    __shared__ float vec[3 * HDIM];
    __shared__ float h1[HDIM];
    __shared__ float h2[128];
    int g = blockIdx.x, t = threadIdx.x;
    vec[t]            = xjk[(size_t)0 * NGRAPH * HDIM + (size_t)g * HDIM + t];
    vec[HDIM + t]     = xjk[(size_t)1 * NGRAPH * HDIM + (size_t)g * HDIM + t];
    vec[2 * HDIM + t] = xjk[(size_t)2 * NGRAPH * HDIM + (size_t)g * HDIM + t];
    __syncthreads();
    float a = jk_b[t];
    for (int k = 0; k < 3 * HDIM; k++) a += vec[k] * jk_w[(size_t)k * HDIM + t];
    h1[t] = a;
    __syncthreads();
    if (t < 128) {
        float a2 = fc1_b[t];
        for (int k = 0; k < HDIM; k++) a2 += h1[k] * fc1_w[(size_t)k * 128 + t];
        h2[t] = tanhf(a2);
    }
    __syncthreads();
    if (t < 64) {
        float a3 = h2[t] * fc2_w[t] + h2[t + 64] * fc2_w[t + 64];
        for (int o = 32; o; o >>= 1) a3 += __shfl_down(a3, o);
        if (t == 0) out[g] = a3 + fc2_b[0];
    }
}

// ---------------------------------------------------------------------------
extern "C" void kernel_launch(void* const* d_in, const int* in_sizes, int n_in,
                              void* d_out, int out_size, void* d_ws, size_t ws_size,
                              hipStream_t stream) {
    const float* x    = (const float*)d_in[0];
    const float* W1   = (const float*)d_in[1];
    const float* b1   = (const float*)d_in[2];
    const float* ln1w = (const float*)d_in[3];
    const float* ln1b = (const float*)d_in[4];
    const float* W2   = (const float*)d_in[5];
    const float* b2   = (const float*)d_in[6];
    const float* ln2w = (const float*)d_in[7];
    const float* ln2b = (const float*)d_in[8];
    const float* W3   = (const float*)d_in[9];
    const float* b3   = (const float*)d_in[10];
    const float* ln3w = (const float*)d_in[11];
    const float* ln3b = (const float*)d_in[12];
    const float* jkw  = (const float*)d_in[13];
    const float* jkb  = (const float*)d_in[14];
    const float* fc1w = (const float*)d_in[15];
    const float* fc1b = (const float*)d_in[16];
    const float* fc2w = (const float*)d_in[17];
    const float* fc2b = (const float*)d_in[18];
    const int*  eidx  = (const int*)d_in[19];
    const int*  batch = (const int*)d_in[20];

    const int E = in_sizes[19] / 2;
    const int n = in_sizes[20];
    const int D = in_sizes[0] / n;  // 128

    const int* src = eidx;
    const int* dst = eidx + E;

    // workspace carve-up (~110 MB):
    char* base = (char*)d_ws;
    size_t o = 0;
    auto alloc = [&](size_t bytes) { void* p = base + o; o += (bytes + 255) & ~(size_t)255; return p; };
    __half* bufZ = (__half*)alloc((size_t)n * HDIM * 2);   // fp16 z
    __half* hPre = (__half*)alloc((size_t)n * HDIM * 2);   // fp16 pre-LN h
    __half* hF   = (__half*)alloc((size_t)n * HDIM * 2);   // fp16 gather table (x16, then h16)
    __half* Wt   = (__half*)alloc((size_t)HDIM * HDIM * 2);// fp16 transposed weights
    int*   csr  = (int*)alloc((size_t)E * 4);
    int*   rs   = (int*)alloc((size_t)(n + 1) * 4);
    int*   cur  = (int*)alloc((size_t)n * 4);
    int*   degi = (int*)alloc((size_t)n * 4);
    float* dinv = (float*)alloc((size_t)n * 4);
    int*   part = (int*)alloc(1024 * 4);
    float* xjk  = (float*)alloc((size_t)3 * NGRAPH * HDIM * 4);
    int*   lidx = (int*)alloc(NGRAPH * 4);
    float* gsum = (float*)alloc(NGRAPH * 4);
    float* gsq  = (float*)alloc(NGRAPH * 4);
    float* mean = (float*)alloc(NGRAPH * 4);
    float* rstd = (float*)alloc(NGRAPH * 4);
    (void)ws_size;

    float* out = (float*)d_out;
    const int GB = (n + 31) / 32;                       // gemm blocks
    const int NB = (n + SCAN_CHUNK - 1) / SCAN_CHUNK;   // scan blocks (49)
    const int AB = 2048;                                // agg blocks (8192 waves)
    const int LT = (int)(((long)n * 64 + 255) / 256);   // ln_tanh blocks

    // --- CSR build + degrees + last-node indices + x->fp16 (once per call) ---
    hipMemsetAsync(degi, 0, (size_t)n * 4, stream);
    hipMemsetAsync(lidx, 0, NGRAPH * 4, stream);
    deg_count_k<<<(E + 255) / 256, 256, 0, stream>>>(dst, degi, E, n);
    dinv_k<<<(n + 255) / 256, 256, 0, stream>>>(degi, dinv, n);
    last_idx_k<<<(n + 255) / 256, 256, 0, stream>>>(batch, lidx, n);
    scan1_k<<<NB, 256, 0, stream>>>(degi, part, n);
    scan2_k<<<1, 1024, 0, stream>>>(part, NB, rs, n);
    scan3_k<<<NB, 256, 0, stream>>>(degi, part, rs, cur, n);
    scatter_k<<<(E + 255) / 256, 256, 0, stream>>>(src, dst, cur, csr, E, n);
    long n4 = (long)n * D / 4;
    cvt_x_k<<<(int)((n4 + 255) / 256), 256, 0, stream>>>(x, hF, n4);  // hF holds x16 [n][128]

    // ---------------- layer 1 (K = 128) ----------------
    agg_csr_k<128><<<AB, 256, 0, stream>>>(rs, csr, hF, dinv, bufZ, n);
    cvt_w_k<<<128, 256, 0, stream>>>(W1, Wt, 128);
    hipMemsetAsync(gsum, 0, 2 * NGRAPH * 4, stream);  // gsum+gsq contiguous
    gcn_gemm_k<128><<<GB, 256, 0, stream>>>(bufZ, Wt, b1, hPre, batch, gsum, gsq, n);
    ln_fin_k<<<1, 64, 0, stream>>>(gsum, gsq, lidx, mean, rstd, n);
    ln_tanh_k<<<LT, 256, 0, stream>>>(hPre, batch, mean, rstd, ln1w, ln1b, hF, n);  // hF now h16 [n][256]
    extract_rows_k<<<NGRAPH, 256, 0, stream>>>(hF, lidx, xjk + 0 * NGRAPH * HDIM, n);

    // ---------------- layer 2 ----------------
    agg_csr_k<256><<<AB, 256, 0, stream>>>(rs, csr, hF, dinv, bufZ, n);
    cvt_w_k<<<256, 256, 0, stream>>>(W2, Wt, 256);
    hipMemsetAsync(gsum, 0, 2 * NGRAPH * 4, stream);
    gcn_gemm_k<256><<<GB, 256, 0, stream>>>(bufZ, Wt, b2, hPre, batch, gsum, gsq, n);
    ln_fin_k<<<1, 64, 0, stream>>>(gsum, gsq, lidx, mean, rstd, n);
    ln_tanh_k<<<LT, 256, 0, stream>>>(hPre, batch, mean, rstd, ln2w, ln2b, hF, n);
    extract_rows_k<<<NGRAPH, 256, 0, stream>>>(hF, lidx, xjk + 1 * NGRAPH * HDIM, n);

    // ---------------- layer 3 ----------------
    agg_csr_k<256><<<AB, 256, 0, stream>>>(rs, csr, hF, dinv, bufZ, n);
    cvt_w_k<<<256, 256, 0, stream>>>(W3, Wt, 256);
    hipMemsetAsync(gsum, 0, 2 * NGRAPH * 4, stream);
    gcn_gemm_k<256><<<GB, 256, 0, stream>>>(bufZ, Wt, b3, hPre, batch, gsum, gsq, n);
    ln_fin_k<<<1, 64, 0, stream>>>(gsum, gsq, lidx, mean, rstd, n);
    ln_tanh_k<<<LT, 256, 0, stream>>>(hPre, batch, mean, rstd, ln3w, ln3b, hF, n);
    extract_rows_k<<<NGRAPH, 256, 0, stream>>>(hF, lidx, xjk + 2 * NGRAPH * HDIM, n);

    // ---------------- head (64 nodes only) ----------------
    final_mlp_k<<<NGRAPH, 256, 0, stream>>>(xjk, jkw, jkb, fc1w, fc1b, fc2w, fc2b, out);
}